// Round 1
// baseline (484.849 us; speedup 1.0000x reference)
//
#include <hip/hip_runtime.h>
#include <math.h>

namespace {
constexpr int S   = 256;   // sequence length == head dim
constexpr int H   = 16;    // heads (for mask indexing)
constexpr int RPB = 8;     // rows per block
constexpr int NT  = 256;   // threads per block
constexpr float SCALE = 0.0625f;  // 1/sqrt(256)
}

__global__ __launch_bounds__(NT) void fused_attn_kernel(
    const float* __restrict__ q,
    const float* __restrict__ k,
    const float* __restrict__ v,
    const float* __restrict__ mask,
    float* __restrict__ out)
{
    __shared__ float qT[S][RPB];    // q rows, transposed: qT[i][si]
    __shared__ float qkT[S][RPB];   // qk,    transposed: qkT[t][si]
    __shared__ float pT[S][RPB];    // softmax probs, transposed
    __shared__ float redbuf[4][RPB];

    const int tid = threadIdx.x;
    constexpr int NRB = S / RPB;    // 32 row-blocks per head
    const int rb = blockIdx.x % NRB;
    const int bh = blockIdx.x / NRB;
    const int h  = bh % H;
    const int s0 = rb * RPB;

    const float* qb = q    + (size_t)bh * S * S;
    const float* kb = k    + (size_t)bh * S * S;
    const float* vb = v    + (size_t)bh * S * S;
    const float* mb = mask + (size_t)h  * S * S + (size_t)s0 * S;
    float*       ob = out  + (size_t)bh * S * S + (size_t)s0 * S;

    // ---- stage q rows into LDS (transposed) ----
    #pragma unroll
    for (int si = 0; si < RPB; ++si)
        qT[tid][si] = qb[(size_t)(s0 + si) * S + tid];
    __syncthreads();

    // ---- stage 1a: qk[si][tid] = dot(q[s0+si], k[tid]) * scale + mask ----
    {
        float acc[RPB];
        #pragma unroll
        for (int si = 0; si < RPB; ++si) acc[si] = 0.f;
        const float* krow = kb + (size_t)tid * S;
        #pragma unroll 4
        for (int i = 0; i < S; ++i) {
            const float kv = krow[i];
            const float4 qa = *reinterpret_cast<const float4*>(&qT[i][0]);
            const float4 qc = *reinterpret_cast<const float4*>(&qT[i][4]);
            acc[0] = fmaf(qa.x, kv, acc[0]);
            acc[1] = fmaf(qa.y, kv, acc[1]);
            acc[2] = fmaf(qa.z, kv, acc[2]);
            acc[3] = fmaf(qa.w, kv, acc[3]);
            acc[4] = fmaf(qc.x, kv, acc[4]);
            acc[5] = fmaf(qc.y, kv, acc[5]);
            acc[6] = fmaf(qc.z, kv, acc[6]);
            acc[7] = fmaf(qc.w, kv, acc[7]);
        }
        float tmp[RPB];
        #pragma unroll
        for (int si = 0; si < RPB; ++si)
            tmp[si] = fmaf(acc[si], SCALE, mb[(size_t)si * S + tid]);
        *reinterpret_cast<float4*>(&qkT[tid][0]) =
            make_float4(tmp[0], tmp[1], tmp[2], tmp[3]);
        *reinterpret_cast<float4*>(&qkT[tid][4]) =
            make_float4(tmp[4], tmp[5], tmp[6], tmp[7]);
    }
    __syncthreads();

    // ---- stage 1b: a1[si] = sum_t qk[si][t] * v[t][tid] ----
    float a1[RPB];
    #pragma unroll
    for (int si = 0; si < RPB; ++si) a1[si] = 0.f;
    #pragma unroll 2
    for (int t = 0; t < S; ++t) {
        const float vv = vb[(size_t)t * S + tid];
        const float4 pa = *reinterpret_cast<const float4*>(&qkT[t][0]);
        const float4 pc = *reinterpret_cast<const float4*>(&qkT[t][4]);
        a1[0] = fmaf(pa.x, vv, a1[0]);
        a1[1] = fmaf(pa.y, vv, a1[1]);
        a1[2] = fmaf(pa.z, vv, a1[2]);
        a1[3] = fmaf(pa.w, vv, a1[3]);
        a1[4] = fmaf(pc.x, vv, a1[4]);
        a1[5] = fmaf(pc.y, vv, a1[5]);
        a1[6] = fmaf(pc.z, vv, a1[6]);
        a1[7] = fmaf(pc.w, vv, a1[7]);
    }

    // ---- masked fill: where mask == 0 -> -1e9 ----
    #pragma unroll
    for (int si = 0; si < RPB; ++si) {
        if (mb[(size_t)si * S + tid] == 0.0f) a1[si] = -1e9f;
    }

    // ---- softmax over the row (axis d == tid across 256 threads) ----
    const int lane = tid & 63;
    const int wv   = tid >> 6;

    #pragma unroll
    for (int si = 0; si < RPB; ++si) {
        float m = a1[si];
        #pragma unroll
        for (int off = 32; off > 0; off >>= 1)
            m = fmaxf(m, __shfl_down(m, off, 64));
        if (lane == 0) redbuf[wv][si] = m;
    }
    __syncthreads();
    float e[RPB];
    #pragma unroll
    for (int si = 0; si < RPB; ++si) {
        const float m = fmaxf(fmaxf(redbuf[0][si], redbuf[1][si]),
                              fmaxf(redbuf[2][si], redbuf[3][si]));
        e[si] = __expf(a1[si] - m);
    }
    __syncthreads();   // redbuf reuse
    #pragma unroll
    for (int si = 0; si < RPB; ++si) {
        float sm = e[si];
        #pragma unroll
        for (int off = 32; off > 0; off >>= 1)
            sm += __shfl_down(sm, off, 64);
        if (lane == 0) redbuf[wv][si] = sm;
    }
    __syncthreads();
    {
        float tmp[RPB];
        #pragma unroll
        for (int si = 0; si < RPB; ++si) {
            const float sm = redbuf[0][si] + redbuf[1][si] +
                             redbuf[2][si] + redbuf[3][si];
            tmp[si] = e[si] / sm;
        }
        *reinterpret_cast<float4*>(&pT[tid][0]) =
            make_float4(tmp[0], tmp[1], tmp[2], tmp[3]);
        *reinterpret_cast<float4*>(&pT[tid][4]) =
            make_float4(tmp[4], tmp[5], tmp[6], tmp[7]);
    }
    __syncthreads();

    // ---- stage 2: out[si][tid] = sum_t p[si][t] * v[t][tid] ----
    float o[RPB];
    #pragma unroll
    for (int si = 0; si < RPB; ++si) o[si] = 0.f;
    #pragma unroll 2
    for (int t = 0; t < S; ++t) {
        const float vv = vb[(size_t)t * S + tid];
        const float4 pa = *reinterpret_cast<const float4*>(&pT[t][0]);
        const float4 pc = *reinterpret_cast<const float4*>(&pT[t][4]);
        o[0] = fmaf(pa.x, vv, o[0]);
        o[1] = fmaf(pa.y, vv, o[1]);
        o[2] = fmaf(pa.z, vv, o[2]);
        o[3] = fmaf(pa.w, vv, o[3]);
        o[4] = fmaf(pc.x, vv, o[4]);
        o[5] = fmaf(pc.y, vv, o[5]);
        o[6] = fmaf(pc.z, vv, o[6]);
        o[7] = fmaf(pc.w, vv, o[7]);
    }
    #pragma unroll
    for (int si = 0; si < RPB; ++si)
        ob[(size_t)si * S + tid] = o[si];
}

extern "C" void kernel_launch(void* const* d_in, const int* in_sizes, int n_in,
                              void* d_out, int out_size, void* d_ws, size_t ws_size,
                              hipStream_t stream) {
    const float* q    = (const float*)d_in[0];
    const float* k    = (const float*)d_in[1];
    const float* v    = (const float*)d_in[2];
    const float* mask = (const float*)d_in[3];
    float* out = (float*)d_out;

    const int nbh = in_sizes[0] / (S * S);   // B*H = 128
    dim3 grid(nbh * (S / RPB));              // 4096 blocks
    fused_attn_kernel<<<grid, NT, 0, stream>>>(q, k, v, mask, out);
}

// Round 2
// 270.418 us; speedup vs baseline: 1.7930x; 1.7930x over previous
//
#include <hip/hip_runtime.h>
#include <math.h>

namespace {
constexpr int S   = 256;   // sequence length == head dim
constexpr int NT  = 256;   // threads per block
constexpr float SCALE = 0.0625f;  // 1/sqrt(256)
}

// ---------------- K transpose: KT[bh][i][t] = k[bh][t][i] ----------------
__global__ __launch_bounds__(NT) void transpose_k_kernel(
    const float* __restrict__ k, float* __restrict__ kt)
{
    __shared__ float tile[64][65];
    const int tileIdx = blockIdx.x & 15;          // 16 tiles of 64x64 per head
    const int bh      = blockIdx.x >> 4;
    const int ti = (tileIdx >> 2) * 64;           // t-origin
    const int tj = (tileIdx & 3) * 64;            // i-origin
    const float* kb = k  + (size_t)bh * S * S;
    float*      ktb = kt + (size_t)bh * S * S;

    const int c  = threadIdx.x & 63;
    const int r4 = threadIdx.x >> 6;              // 0..3

    #pragma unroll
    for (int rr = 0; rr < 64; rr += 4)
        tile[rr + r4][c] = kb[(size_t)(ti + rr + r4) * S + tj + c];
    __syncthreads();
    #pragma unroll
    for (int rr = 0; rr < 64; rr += 4)
        ktb[(size_t)(tj + rr + r4) * S + ti + c] = tile[c][rr + r4];
}

// ---------------- fused attention, 16 rows per block ----------------
template <int RPB>
__global__ __launch_bounds__(NT) void fused_attn_rpb(
    const float* __restrict__ q,
    const float* __restrict__ kt,     // transposed K
    const float* __restrict__ v,
    const float* __restrict__ mask,
    float* __restrict__ out,
    int nbh, int H, int swizzle)
{
    __shared__ float qT[S][RPB];      // qT[i][si]
    __shared__ float sT[S][RPB];      // qk then P, transposed [t][si]
    __shared__ float redbuf[4][RPB];

    const int tid = threadIdx.x;
    constexpr int NRB = S / RPB;

    int bh, rb;
    if (swizzle) {
        // block x -> XCD x%8 (round-robin assumption); co-locate a head's
        // NRB blocks on one XCD for L2 reuse of KT and V.
        const int xcd  = blockIdx.x & 7;
        const int slot = blockIdx.x >> 3;
        const int hpx  = nbh >> 3;                // heads per xcd
        bh = xcd * hpx + (slot % hpx);
        rb = slot / hpx;
    } else {
        bh = blockIdx.x / NRB;
        rb = blockIdx.x % NRB;
    }
    const int h  = bh % H;
    const int s0 = rb * RPB;

    const float* qb  = q    + (size_t)bh * S * S;
    const float* ktb = kt   + (size_t)bh * S * S;
    const float* vb  = v    + (size_t)bh * S * S;
    const float* mb  = mask + (size_t)h  * S * S + (size_t)s0 * S;
    float*       ob  = out  + (size_t)bh * S * S + (size_t)s0 * S;

    // ---- stage q rows into LDS (transposed) ----
    #pragma unroll
    for (int si = 0; si < RPB; ++si)
        qT[tid][si] = qb[(size_t)(s0 + si) * S + tid];
    __syncthreads();

    // ---- stage 1a: qk[si][tid] = dot(q[s0+si], k[tid]) * scale + mask ----
    {
        float acc[RPB];
        #pragma unroll
        for (int si = 0; si < RPB; ++si) acc[si] = 0.f;
        #pragma unroll 4
        for (int i = 0; i < S; ++i) {
            const float kv = ktb[(size_t)i * S + tid];   // coalesced
            #pragma unroll
            for (int si4 = 0; si4 < RPB; si4 += 4) {
                const float4 qa = *reinterpret_cast<const float4*>(&qT[i][si4]);
                acc[si4 + 0] = fmaf(qa.x, kv, acc[si4 + 0]);
                acc[si4 + 1] = fmaf(qa.y, kv, acc[si4 + 1]);
                acc[si4 + 2] = fmaf(qa.z, kv, acc[si4 + 2]);
                acc[si4 + 3] = fmaf(qa.w, kv, acc[si4 + 3]);
            }
        }
        #pragma unroll
        for (int si4 = 0; si4 < RPB; si4 += 4) {
            float4 t4;
            t4.x = fmaf(acc[si4 + 0], SCALE, mb[(size_t)(si4 + 0) * S + tid]);
            t4.y = fmaf(acc[si4 + 1], SCALE, mb[(size_t)(si4 + 1) * S + tid]);
            t4.z = fmaf(acc[si4 + 2], SCALE, mb[(size_t)(si4 + 2) * S + tid]);
            t4.w = fmaf(acc[si4 + 3], SCALE, mb[(size_t)(si4 + 3) * S + tid]);
            *reinterpret_cast<float4*>(&sT[tid][si4]) = t4;
        }
    }
    __syncthreads();

    // ---- stage 1b: a1[si] = sum_t qk[si][t] * v[t][tid] ----
    float a1[RPB];
    #pragma unroll
    for (int si = 0; si < RPB; ++si) a1[si] = 0.f;
    #pragma unroll 2
    for (int t = 0; t < S; ++t) {
        const float vv = vb[(size_t)t * S + tid];        // coalesced
        #pragma unroll
        for (int si4 = 0; si4 < RPB; si4 += 4) {
            const float4 pa = *reinterpret_cast<const float4*>(&sT[t][si4]);
            a1[si4 + 0] = fmaf(pa.x, vv, a1[si4 + 0]);
            a1[si4 + 1] = fmaf(pa.y, vv, a1[si4 + 1]);
            a1[si4 + 2] = fmaf(pa.z, vv, a1[si4 + 2]);
            a1[si4 + 3] = fmaf(pa.w, vv, a1[si4 + 3]);
        }
    }

    // ---- masked fill: where mask == 0 -> -1e9 ----
    #pragma unroll
    for (int si = 0; si < RPB; ++si)
        if (mb[(size_t)si * S + tid] == 0.0f) a1[si] = -1e9f;

    // ---- softmax over d (= tid across 256 threads) ----
    const int lane = tid & 63;
    const int wv   = tid >> 6;

    #pragma unroll
    for (int si = 0; si < RPB; ++si) {
        float m = a1[si];
        #pragma unroll
        for (int off = 32; off > 0; off >>= 1)
            m = fmaxf(m, __shfl_down(m, off, 64));
        if (lane == 0) redbuf[wv][si] = m;
    }
    __syncthreads();
    float e[RPB];
    #pragma unroll
    for (int si = 0; si < RPB; ++si) {
        const float m = fmaxf(fmaxf(redbuf[0][si], redbuf[1][si]),
                              fmaxf(redbuf[2][si], redbuf[3][si]));
        e[si] = __expf(a1[si] - m);
    }
    __syncthreads();   // redbuf reuse
    #pragma unroll
    for (int si = 0; si < RPB; ++si) {
        float sm = e[si];
        #pragma unroll
        for (int off = 32; off > 0; off >>= 1)
            sm += __shfl_down(sm, off, 64);
        if (lane == 0) redbuf[wv][si] = sm;
    }
    __syncthreads();
    #pragma unroll
    for (int si4 = 0; si4 < RPB; si4 += 4) {
        float4 t4;
        #pragma unroll
        for (int j = 0; j < 4; ++j) {
            const int si = si4 + j;
            const float sm = redbuf[0][si] + redbuf[1][si] +
                             redbuf[2][si] + redbuf[3][si];
            (&t4.x)[j] = e[si] / sm;
        }
        *reinterpret_cast<float4*>(&sT[tid][si4]) = t4;   // P, transposed
    }
    __syncthreads();

    // ---- stage 2: out[si][tid] = sum_t P[si][t] * v[t][tid] ----
    float o[RPB];
    #pragma unroll
    for (int si = 0; si < RPB; ++si) o[si] = 0.f;
    #pragma unroll 2
    for (int t = 0; t < S; ++t) {
        const float vv = vb[(size_t)t * S + tid];
        #pragma unroll
        for (int si4 = 0; si4 < RPB; si4 += 4) {
            const float4 pa = *reinterpret_cast<const float4*>(&sT[t][si4]);
            o[si4 + 0] = fmaf(pa.x, vv, o[si4 + 0]);
            o[si4 + 1] = fmaf(pa.y, vv, o[si4 + 1]);
            o[si4 + 2] = fmaf(pa.z, vv, o[si4 + 2]);
            o[si4 + 3] = fmaf(pa.w, vv, o[si4 + 3]);
        }
    }
    #pragma unroll
    for (int si = 0; si < RPB; ++si)
        ob[(size_t)si * S + tid] = o[si];
}

// ---------------- fallback (round-1 kernel, no workspace) ----------------
__global__ __launch_bounds__(NT) void fused_attn_fallback(
    const float* __restrict__ q, const float* __restrict__ k,
    const float* __restrict__ v, const float* __restrict__ mask,
    float* __restrict__ out, int H)
{
    constexpr int RPB = 8;
    __shared__ float qT[S][RPB];
    __shared__ float sT[S][RPB];
    __shared__ float redbuf[4][RPB];

    const int tid = threadIdx.x;
    constexpr int NRB = S / RPB;
    const int rb = blockIdx.x % NRB;
    const int bh = blockIdx.x / NRB;
    const int h  = bh % H;
    const int s0 = rb * RPB;

    const float* qb = q    + (size_t)bh * S * S;
    const float* kb = k    + (size_t)bh * S * S;
    const float* vb = v    + (size_t)bh * S * S;
    const float* mb = mask + (size_t)h  * S * S + (size_t)s0 * S;
    float*       ob = out  + (size_t)bh * S * S + (size_t)s0 * S;

    #pragma unroll
    for (int si = 0; si < RPB; ++si)
        qT[tid][si] = qb[(size_t)(s0 + si) * S + tid];
    __syncthreads();

    {
        float acc[RPB];
        #pragma unroll
        for (int si = 0; si < RPB; ++si) acc[si] = 0.f;
        const float* krow = kb + (size_t)tid * S;
        #pragma unroll 4
        for (int i = 0; i < S; ++i) {
            const float kv = krow[i];
            #pragma unroll
            for (int si4 = 0; si4 < RPB; si4 += 4) {
                const float4 qa = *reinterpret_cast<const float4*>(&qT[i][si4]);
                acc[si4+0] = fmaf(qa.x, kv, acc[si4+0]);
                acc[si4+1] = fmaf(qa.y, kv, acc[si4+1]);
                acc[si4+2] = fmaf(qa.z, kv, acc[si4+2]);
                acc[si4+3] = fmaf(qa.w, kv, acc[si4+3]);
            }
        }
        #pragma unroll
        for (int si4 = 0; si4 < RPB; si4 += 4) {
            float4 t4;
            t4.x = fmaf(acc[si4+0], SCALE, mb[(size_t)(si4+0)*S + tid]);
            t4.y = fmaf(acc[si4+1], SCALE, mb[(size_t)(si4+1)*S + tid]);
            t4.z = fmaf(acc[si4+2], SCALE, mb[(size_t)(si4+2)*S + tid]);
            t4.w = fmaf(acc[si4+3], SCALE, mb[(size_t)(si4+3)*S + tid]);
            *reinterpret_cast<float4*>(&sT[tid][si4]) = t4;
        }
    }
    __syncthreads();

    float a1[RPB];
    #pragma unroll
    for (int si = 0; si < RPB; ++si) a1[si] = 0.f;
    #pragma unroll 2
    for (int t = 0; t < S; ++t) {
        const float vv = vb[(size_t)t * S + tid];
        #pragma unroll
        for (int si4 = 0; si4 < RPB; si4 += 4) {
            const float4 pa = *reinterpret_cast<const float4*>(&sT[t][si4]);
            a1[si4+0] = fmaf(pa.x, vv, a1[si4+0]);
            a1[si4+1] = fmaf(pa.y, vv, a1[si4+1]);
            a1[si4+2] = fmaf(pa.z, vv, a1[si4+2]);
            a1[si4+3] = fmaf(pa.w, vv, a1[si4+3]);
        }
    }
    #pragma unroll
    for (int si = 0; si < RPB; ++si)
        if (mb[(size_t)si * S + tid] == 0.0f) a1[si] = -1e9f;

    const int lane = tid & 63;
    const int wv   = tid >> 6;
    #pragma unroll
    for (int si = 0; si < RPB; ++si) {
        float m = a1[si];
        #pragma unroll
        for (int off = 32; off > 0; off >>= 1)
            m = fmaxf(m, __shfl_down(m, off, 64));
        if (lane == 0) redbuf[wv][si] = m;
    }
    __syncthreads();
    float e[RPB];
    #pragma unroll
    for (int si = 0; si < RPB; ++si) {
        const float m = fmaxf(fmaxf(redbuf[0][si], redbuf[1][si]),
                              fmaxf(redbuf[2][si], redbuf[3][si]));
        e[si] = __expf(a1[si] - m);
    }
    __syncthreads();
    #pragma unroll
    for (int si = 0; si < RPB; ++si) {
        float sm = e[si];
        #pragma unroll
        for (int off = 32; off > 0; off >>= 1)
            sm += __shfl_down(sm, off, 64);
        if (lane == 0) redbuf[wv][si] = sm;
    }
    __syncthreads();
    #pragma unroll
    for (int si4 = 0; si4 < RPB; si4 += 4) {
        float4 t4;
        #pragma unroll
        for (int j = 0; j < 4; ++j) {
            const int si = si4 + j;
            const float sm = redbuf[0][si] + redbuf[1][si] +
                             redbuf[2][si] + redbuf[3][si];
            (&t4.x)[j] = e[si] / sm;
        }
        *reinterpret_cast<float4*>(&sT[tid][si4]) = t4;
    }
    __syncthreads();

    float o[RPB];
    #pragma unroll
    for (int si = 0; si < RPB; ++si) o[si] = 0.f;
    #pragma unroll 2
    for (int t = 0; t < S; ++t) {
        const float vv = vb[(size_t)t * S + tid];
        #pragma unroll
        for (int si4 = 0; si4 < RPB; si4 += 4) {
            const float4 pa = *reinterpret_cast<const float4*>(&sT[t][si4]);
            o[si4+0] = fmaf(pa.x, vv, o[si4+0]);
            o[si4+1] = fmaf(pa.y, vv, o[si4+1]);
            o[si4+2] = fmaf(pa.z, vv, o[si4+2]);
            o[si4+3] = fmaf(pa.w, vv, o[si4+3]);
        }
    }
    #pragma unroll
    for (int si = 0; si < RPB; ++si)
        ob[(size_t)si * S + tid] = o[si];
}

extern "C" void kernel_launch(void* const* d_in, const int* in_sizes, int n_in,
                              void* d_out, int out_size, void* d_ws, size_t ws_size,
                              hipStream_t stream) {
    const float* q    = (const float*)d_in[0];
    const float* k    = (const float*)d_in[1];
    const float* v    = (const float*)d_in[2];
    const float* mask = (const float*)d_in[3];
    float* out = (float*)d_out;

    const int nbh = in_sizes[0] / (S * S);   // B*H
    const int H   = in_sizes[3] / (S * S);   // heads (mask is [1,H,S,S])
    const size_t kt_bytes = (size_t)nbh * S * S * sizeof(float);

    if (ws_size >= kt_bytes) {
        float* kt = (float*)d_ws;
        transpose_k_kernel<<<dim3(nbh * 16), NT, 0, stream>>>(k, kt);
        constexpr int RPB = 16;
        const int grid = nbh * (S / RPB);
        const int swz = (nbh % 8 == 0) ? 1 : 0;
        fused_attn_rpb<RPB><<<dim3(grid), NT, 0, stream>>>(
            q, kt, v, mask, out, nbh, H, swz);
    } else {
        fused_attn_fallback<<<dim3(nbh * (S / 8)), NT, 0, stream>>>(
            q, k, v, mask, out, H);
    }
}